// Round 14
// baseline (433.180 us; speedup 1.0000x reference)
//
#include <hip/hip_runtime.h>
#include <hip/hip_bf16.h>
#include <math.h>

#define BF16 __hip_bfloat16

typedef __bf16 bf16x8 __attribute__((ext_vector_type(8)));
typedef float  f32x4  __attribute__((ext_vector_type(4)));
typedef float  f32x16 __attribute__((ext_vector_type(16)));
typedef int    i32x4  __attribute__((ext_vector_type(4)));

// branch-free erf (Abramowitz-Stegun 7.1.26, |err| < 1.5e-7)
__device__ inline float gelu_erf(float x) {
  float xs = x * 0.70710678118654752f;
  float a = fabsf(xs);
  float t = __builtin_amdgcn_rcpf(1.0f + 0.3275911f * a);
  float p = 1.061405429f;
  p = p * t - 1.453152027f;
  p = p * t + 1.421413741f;
  p = p * t - 0.284496736f;
  p = p * t + 0.254829592f;
  float e = __expf(-a * a);
  float y = 1.0f - p * t * e;
  float s = copysignf(y, xs);
  return 0.5f * x * (1.0f + s);
}

__device__ inline bf16x8 asbf8(i32x4 v) { union { i32x4 i; bf16x8 b; } u; u.i = v; return u.b; }

__device__ inline i32x4 aload16(const char* p) {
  i32x4 d;
  asm volatile("global_load_dwordx4 %0, %1, off" : "=v"(d) : "v"(p));
  return d;
}

template <int N> __device__ inline void vmwait() {
  if constexpr (N == 0)      asm volatile("s_waitcnt vmcnt(0)" ::: "memory");
  else if constexpr (N == 4) asm volatile("s_waitcnt vmcnt(4)" ::: "memory");
  else                       asm volatile("s_waitcnt vmcnt(8)" ::: "memory");
  __builtin_amdgcn_sched_barrier(0);
}

// ---- non-temporal access helpers (native ext_vector types: HIP float4 is a
// class and the builtin rejects it) ----
__device__ inline f32x4 ntload4(const float* p) {
  return __builtin_nontemporal_load((const f32x4*)p);
}
__device__ inline void ntstore4(float* p, f32x4 v) {
  __builtin_nontemporal_store(v, (f32x4*)p);
}
__device__ inline float ntloadf(const float* p) { return __builtin_nontemporal_load(p); }
__device__ inline void ntstoreu16(unsigned short* p, unsigned short v) {
  __builtin_nontemporal_store(v, p);
}
__device__ inline unsigned short ntloadu16(const unsigned short* p) {
  return __builtin_nontemporal_load(p);
}

struct WPtrs { const float* p[9]; };
struct FArgs { const BF16* w[5]; const float* b[5]; };

// ---------------- small prep kernels ----------------
// Weights in MFMA-fragment order:
//   element = wc*16384 + nc*4096 + kt*512 + (fq*16+fr)*8 + e
//   source  = W[wc*64+nc*16+fr][kt*32+fq*8+e]       (wc: col-group 0..3)
__global__ void cast_w_kernel(WPtrs wp, BF16* __restrict__ out) {
  int i = blockIdx.x * 256 + threadIdx.x;   // < 9*65536
  int seg = i >> 16, d = i & 65535;
  int e = d & 7, lane = (d >> 3) & 63, kt = (d >> 9) & 7;
  int nc = (d >> 12) & 3, wc = (d >> 14) & 3;
  int fr = lane & 15, fq = lane >> 4;
  int row = wc * 64 + nc * 16 + fr, col = kt * 32 + fq * 8 + e;
  out[i] = __float2bfloat16(wp.p[seg][row * 256 + col]);
}

// W~[p, h*32+d] = sum_j mix_w[p, h*32+j] * latent_q[h*32+j, d], fragment-ordered
__global__ void build_wtilde(const float* __restrict__ mixw, const float* __restrict__ lq,
                             BF16* __restrict__ wt) {
  int p = blockIdx.x, c = threadIdx.x;
  int h = c >> 5, d = c & 31;
  float s = 0.f;
#pragma unroll
  for (int j = 0; j < 32; ++j)
    s += mixw[p * 256 + h * 32 + j] * lq[(h * 32 + j) * 32 + d];
  int wc = p >> 6, nc = (p >> 4) & 3, fr = p & 15;
  int kt = c >> 5, fq = (c >> 3) & 3, e = c & 7;
  int dst = ((((wc * 4 + nc) * 8 + kt) * 64) + (fq * 16 + fr)) * 8 + e;
  wt[dst] = __float2bfloat16(s);
}

// ---------------- helpers ----------------
__device__ inline void issue4(i32x4 (&buf)[4], const char* wlane, int kt) {
#pragma unroll
  for (int nc = 0; nc < 4; ++nc)
    buf[nc] = aload16(wlane + (nc * 8 + kt) * 1024);
}

__device__ inline void loada4(bf16x8 (&dst)[4], const char* act, int kt, int fr, int fq) {
#pragma unroll
  for (int nr = 0; nr < 4; ++nr) {
    int r = nr * 16 + fr;
    dst[nr] = *(const bf16x8*)(act + r * 512 + ((kt * 64 + fq * 16) ^ ((r & 7) << 4)));
  }
}

__device__ inline void mfma16w(f32x4 (&acc)[4][4], const i32x4 (&wbuf)[4], const bf16x8 (&af)[4]) {
#pragma unroll
  for (int nr = 0; nr < 4; ++nr)
#pragma unroll
    for (int nc = 0; nc < 4; ++nc)
      acc[nr][nc] = __builtin_amdgcn_mfma_f32_16x16x32_bf16(asbf8(wbuf[nc]), af[nr], acc[nr][nc], 0, 0, 0);
}

// 8-kt pipelined GEMM over the resident act tile (R6-verified structure)
__device__ inline void kloop8(f32x4 (&acc)[4][4], const char* wlane, const char* act,
                              int fr, int fq) {
  i32x4 wb0[4], wb1[4], wb2[4];
  bf16x8 afA[4], afB[4];
  issue4(wb0, wlane, 0);
  issue4(wb1, wlane, 1);
  loada4(afA, act, 0, fr, fq);
  issue4(wb2, wlane, 2); loada4(afB, act, 1, fr, fq);
  vmwait<8>(); mfma16w(acc, wb0, afA);
  issue4(wb0, wlane, 3); loada4(afA, act, 2, fr, fq);
  vmwait<8>(); mfma16w(acc, wb1, afB);
  issue4(wb1, wlane, 4); loada4(afB, act, 3, fr, fq);
  vmwait<8>(); mfma16w(acc, wb2, afA);
  issue4(wb2, wlane, 5); loada4(afA, act, 4, fr, fq);
  vmwait<8>(); mfma16w(acc, wb0, afB);
  issue4(wb0, wlane, 6); loada4(afB, act, 5, fr, fq);
  vmwait<8>(); mfma16w(acc, wb1, afA);
  issue4(wb1, wlane, 7); loada4(afA, act, 6, fr, fq);
  vmwait<8>(); mfma16w(acc, wb2, afB);
  loada4(afB, act, 7, fr, fq);
  vmwait<4>(); mfma16w(acc, wb0, afA);
  vmwait<0>(); mfma16w(acc, wb1, afB);
}

// ---------------- k-chain: 4 MLP layers + mixed + softmax-N stats ----------------
__global__ __launch_bounds__(256, 3) void fused_k_mixed(
    const float* __restrict__ xin, FArgs args,
    float* __restrict__ mixed,
    float* __restrict__ pm, float* __restrict__ ps) {
  __shared__ __align__(16) char act[64 * 512];
  const int tid = threadIdx.x;
  const int blk = blockIdx.x;
  const int wc = tid >> 6, lane = tid & 63;
  const int fr = lane & 15, fq = lane >> 4;
  const size_t row0 = (size_t)blk * 64;

  // ---- stage input tile into swizzled LDS (nt: x is a 134MB stream) ----
  {
    const float* xg = xin + row0 * 256;
#pragma unroll
    for (int rep = 0; rep < 16; ++rep) {
      int i = rep * 256 + tid;               // float4 index in tile (4096 total)
      int r = i >> 6, c4 = (i & 63) << 2;
      f32x4 v = ntload4(xg + r * 256 + c4);
      union { __bf16 h[4]; unsigned long long u; } p;
      p.h[0] = (__bf16)v[0]; p.h[1] = (__bf16)v[1];
      p.h[2] = (__bf16)v[2]; p.h[3] = (__bf16)v[3];
      int byte = r * 512 + ((c4 * 2) ^ ((r & 7) << 4));
      *(unsigned long long*)(act + byte) = p.u;
    }
  }
  __syncthreads();

#pragma unroll 1
  for (int L = 0; L < 5; ++L) {
    const char* wlane = (const char*)args.w[L] + (size_t)(wc * 2048 + lane) * 16;
    f32x4 acc[4][4];
#pragma unroll
    for (int nr = 0; nr < 4; ++nr)
#pragma unroll
      for (int nc = 0; nc < 4; ++nc)
#pragma unroll
        for (int j = 0; j < 4; ++j) acc[nr][nc][j] = 0.f;

    kloop8(acc, wlane, act, fr, fq);
    __syncthreads();   // all act reads done before any epilogue write

    if (L == 4) {
      // mixed epilogue: f32 global (nt stream) + per-column max/sumexp partials
      float* mg = mixed + row0 * 256;
#pragma unroll
      for (int nc = 0; nc < 4; ++nc) {
#pragma unroll
        for (int nr = 0; nr < 4; ++nr) {
          f32x4 st = { acc[nr][nc][0], acc[nr][nc][1], acc[nr][nc][2], acc[nr][nc][3] };
          ntstore4(mg + (size_t)(nr * 16 + fr) * 256 + wc * 64 + nc * 16 + fq * 4, st);
        }
        float mx[4], sm[4];
#pragma unroll
        for (int jj = 0; jj < 4; ++jj) {
          float m0 = fmaxf(fmaxf(acc[0][nc][jj], acc[1][nc][jj]),
                           fmaxf(acc[2][nc][jj], acc[3][nc][jj]));
#pragma unroll
          for (int d = 1; d < 16; d <<= 1) m0 = fmaxf(m0, __shfl_xor(m0, d));
          float s0 = 0.f;
#pragma unroll
          for (int nr = 0; nr < 4; ++nr) s0 += __expf(acc[nr][nc][jj] - m0);
#pragma unroll
          for (int d = 1; d < 16; d <<= 1) s0 += __shfl_xor(s0, d);
          mx[jj] = m0; sm[jj] = s0;
        }
        if (fr == 0) {
          int col = wc * 64 + nc * 16 + fq * 4;
          *(float4*)(pm + (size_t)blk * 256 + col) = {mx[0], mx[1], mx[2], mx[3]};
          *(float4*)(ps + (size_t)blk * 256 + col) = {sm[0], sm[1], sm[2], sm[3]};
        }
      }
    } else {
      const float* bb = args.b[L];
#pragma unroll
      for (int nc = 0; nc < 4; ++nc) {
        float4 b4 = *(const float4*)(bb + wc * 64 + nc * 16 + fq * 4);
#pragma unroll
        for (int nr = 0; nr < 4; ++nr) {
          int r = nr * 16 + fr;
          int cb2 = wc * 128 + nc * 32 + fq * 8;
          int byte = r * 512 + (cb2 ^ ((r & 7) << 4));
          union { __bf16 h[4]; unsigned long long u; } res, w2;
          res.u = *(unsigned long long*)(act + byte);
          float o0 = acc[nr][nc][0] + b4.x;
          float o1 = acc[nr][nc][1] + b4.y;
          float o2 = acc[nr][nc][2] + b4.z;
          float o3 = acc[nr][nc][3] + b4.w;
          if (L < 3) { o0 = gelu_erf(o0); o1 = gelu_erf(o1);
                       o2 = gelu_erf(o2); o3 = gelu_erf(o3); }
          w2.h[0] = (__bf16)((float)res.h[0] + o0);
          w2.h[1] = (__bf16)((float)res.h[1] + o1);
          w2.h[2] = (__bf16)((float)res.h[2] + o2);
          w2.h[3] = (__bf16)((float)res.h[3] + o3);
          *(unsigned long long*)(act + byte) = w2.u;
        }
      }
      __syncthreads();
    }
  }
}

// ---------------- softmax-over-N merge ----------------
__global__ void softmax_merge(const float* __restrict__ pm, const float* __restrict__ ps,
                              float* __restrict__ Mf, float* __restrict__ Sf) {
  int b = blockIdx.x, t = threadIdx.x;
  const float* pmb = pm + (size_t)b * 512 * 256;
  const float* psb = ps + (size_t)b * 512 * 256;
  float m = -3.0e38f, s = 0.f;
  for (int c = 0; c < 512; ++c) {
    float m2 = pmb[c * 256 + t];
    float s2 = psb[c * 256 + t];
    float mn = fmaxf(m, m2);
    s = s * __expf(m - mn) + s2 * __expf(m2 - mn);
    m = mn;
  }
  Mf[b * 256 + t] = m;
  Sf[b * 256 + t] = 1.f / s;
}

// ---------------- v-chain + fused z-partial ----------------
// v stays in LDS (never hits HBM); z-partials use global Mf; bf16 zpart.
__global__ __launch_bounds__(256, 3) void fused_v_z(
    const float* __restrict__ xin, FArgs args,
    const float* __restrict__ mixed, const float* __restrict__ Mf,
    BF16* __restrict__ zpart) {
  __shared__ __align__(16) char act[64 * 512];
  const int tid = threadIdx.x;
  const int blk = blockIdx.x;
  const int wc = tid >> 6, lane = tid & 63;
  const int fr = lane & 15, fq = lane >> 4;
  const size_t row0 = (size_t)blk * 64;

  // ---- stage input tile into swizzled LDS (nt stream) ----
  {
    const float* xg = xin + row0 * 256;
#pragma unroll
    for (int rep = 0; rep < 16; ++rep) {
      int i = rep * 256 + tid;
      int r = i >> 6, c4 = (i & 63) << 2;
      f32x4 v = ntload4(xg + r * 256 + c4);
      union { __bf16 h[4]; unsigned long long u; } p;
      p.h[0] = (__bf16)v[0]; p.h[1] = (__bf16)v[1];
      p.h[2] = (__bf16)v[2]; p.h[3] = (__bf16)v[3];
      int byte = r * 512 + ((c4 * 2) ^ ((r & 7) << 4));
      *(unsigned long long*)(act + byte) = p.u;
    }
  }
  __syncthreads();

  // ---- 4 MLP layers, result stays in act LDS ----
#pragma unroll 1
  for (int L = 0; L < 4; ++L) {
    const char* wlane = (const char*)args.w[L] + (size_t)(wc * 2048 + lane) * 16;
    f32x4 acc[4][4];
#pragma unroll
    for (int nr = 0; nr < 4; ++nr)
#pragma unroll
      for (int nc = 0; nc < 4; ++nc)
#pragma unroll
        for (int j = 0; j < 4; ++j) acc[nr][nc][j] = 0.f;

    kloop8(acc, wlane, act, fr, fq);
    __syncthreads();

    const float* bb = args.b[L];
#pragma unroll
    for (int nc = 0; nc < 4; ++nc) {
      float4 b4 = *(const float4*)(bb + wc * 64 + nc * 16 + fq * 4);
#pragma unroll
      for (int nr = 0; nr < 4; ++nr) {
        int r = nr * 16 + fr;
        int cb2 = wc * 128 + nc * 32 + fq * 8;
        int byte = r * 512 + (cb2 ^ ((r & 7) << 4));
        union { __bf16 h[4]; unsigned long long u; } res, w2;
        res.u = *(unsigned long long*)(act + byte);
        float o0 = acc[nr][nc][0] + b4.x;
        float o1 = acc[nr][nc][1] + b4.y;
        float o2 = acc[nr][nc][2] + b4.z;
        float o3 = acc[nr][nc][3] + b4.w;
        if (L < 3) { o0 = gelu_erf(o0); o1 = gelu_erf(o1);
                     o2 = gelu_erf(o2); o3 = gelu_erf(o3); }
        w2.h[0] = (__bf16)((float)res.h[0] + o0);
        w2.h[1] = (__bf16)((float)res.h[1] + o1);
        w2.h[2] = (__bf16)((float)res.h[2] + o2);
        w2.h[3] = (__bf16)((float)res.h[3] + o3);
        *(unsigned long long*)(act + byte) = w2.u;
      }
    }
    __syncthreads();
  }

  // ---- z-partial phase: v from LDS, enc from exp(mixed - Mf) (nt reads) ----
  const int l31 = lane & 31, kh = lane >> 5;
  const int b = (int)(row0 >> 15);
  for (int hi = 0; hi < 2; ++hi) {
    int h = wc * 2 + hi;                  // wave wc handles heads 2wc, 2wc+1
    int col = h * 32 + l31;
    float Mp = Mf[b * 256 + col];
    f32x16 zacc;
#pragma unroll
    for (int r = 0; r < 16; ++r) zacc[r] = 0.f;
#pragma unroll
    for (int s = 0; s < 4; ++s) {         // K = 64 rows in 4 steps of 16
      bf16x8 ea, vb;
      int rl0 = s * 16 + kh * 8;
      size_t nbase = row0 + rl0;
#pragma unroll
      for (int j = 0; j < 8; ++j) {
        float xv = __expf(ntloadf(mixed + (nbase + j) * 256 + col) - Mp);
        ea[j] = (__bf16)xv;
        int rl = rl0 + j;
        vb[j] = *(const __bf16*)(act + rl * 512 + ((col * 2) ^ ((rl & 7) << 4)));
      }
      zacc = __builtin_amdgcn_mfma_f32_32x32x16_bf16(ea, vb, zacc, 0, 0, 0);
    }
    BF16* zp = zpart + (size_t)blk * 8192 + h * 1024;
#pragma unroll
    for (int reg = 0; reg < 16; ++reg) {
      int m = (reg & 3) + 8 * (reg >> 2) + 4 * kh;
      union { BF16 h; unsigned short u; } cv;
      cv.h = __float2bfloat16(zacc[reg]);
      ntstoreu16((unsigned short*)(zp + m * 32 + l31), cv.u);
    }
  }
}

__global__ void z_merge(const BF16* __restrict__ zpart, const float* __restrict__ Sf,
                        float* __restrict__ z) {
  int i = blockIdx.x * 256 + threadIdx.x;   // [0, 4*8192)
  int b = i >> 13, j = i & 8191;
  int p = j >> 5;                           // h*32 + m
  float s = 0.f;
  for (int c = 0; c < 512; ++c) {
    union { unsigned short u; BF16 h; } cv;
    cv.u = ntloadu16((const unsigned short*)(zpart + ((size_t)(b * 512 + c)) * 8192 + j));
    s += __bfloat162float(cv.h);
  }
  z[i] = s * Sf[b * 256 + p];
}

// ---------------- decode + final projection fused ----------------
__global__ __launch_bounds__(256, 3) void decode_final(
    const float* __restrict__ mixed, const float* __restrict__ z,
    const BF16* __restrict__ wfin, const float* __restrict__ bias,
    float* __restrict__ fout) {
  __shared__ __align__(16) char act[64 * 512];
  const int tid = threadIdx.x, blk = blockIdx.x;
  const int wid = tid >> 6, lane = tid & 63;
  const int l31 = lane & 31, kh = lane >> 5;
  const int fr = lane & 15, fq = lane >> 4;
  const size_t row0 = (size_t)blk * 64;
  const int b = (int)(row0 >> 15);

  // ---- phase 1: decode into LDS o-tile (mixed reads nt; z stays cached) ----
  for (int hi = 0; hi < 2; ++hi) {
    int h = (wid << 1) + hi;
    bf16x8 zf[2];
#pragma unroll
    for (int ks = 0; ks < 2; ++ks)
#pragma unroll
      for (int j = 0; j < 8; ++j)
        zf[ks][j] = (__bf16)z[b * 8192 + h * 1024 + (ks * 16 + kh * 8 + j) * 32 + l31];
#pragma unroll 1
    for (int s = 0; s < 2; ++s) {
      size_t n = row0 + s * 32 + l31;
      const float* mrow = mixed + n * 256 + h * 32;
      float xv[16];
#pragma unroll
      for (int ks = 0; ks < 2; ++ks) {
        f32x4 a  = ntload4(mrow + ks * 16 + kh * 8);
        f32x4 c4 = ntload4(mrow + ks * 16 + kh * 8 + 4);
        xv[ks * 8 + 0] = a[0];  xv[ks * 8 + 1] = a[1];  xv[ks * 8 + 2] = a[2];  xv[ks * 8 + 3] = a[3];
        xv[ks * 8 + 4] = c4[0]; xv[ks * 8 + 5] = c4[1]; xv[ks * 8 + 6] = c4[2]; xv[ks * 8 + 7] = c4[3];
      }
      float mx = xv[0];
#pragma unroll
      for (int i = 1; i < 16; ++i) mx = fmaxf(mx, xv[i]);
      mx = fmaxf(mx, __shfl_xor(mx, 32));
      float sm = 0.f, ev[16];
#pragma unroll
      for (int i = 0; i < 16; ++i) { ev[i] = __expf(xv[i] - mx); sm += ev[i]; }
      sm += __shfl_xor(sm, 32);
      float inv = 1.f / sm;
      bf16x8 af[2];
#pragma unroll
      for (int ks = 0; ks < 2; ++ks)
#pragma unroll
        for (int j = 0; j < 8; ++j) af[ks][j] = (__bf16)(ev[ks * 8 + j] * inv);
      f32x16 acc;
#pragma unroll
      for (int r = 0; r < 16; ++r) acc[r] = 0.f;
      acc = __builtin_amdgcn_mfma_f32_32x32x16_bf16(af[0], zf[0], acc, 0, 0, 0);
      acc = __builtin_amdgcn_mfma_f32_32x32x16_bf16(af[1], zf[1], acc, 0, 0, 0);
#pragma unroll
      for (int reg = 0; reg < 16; ++reg) {
        int rl = s * 32 + (reg & 3) + 8 * (reg >> 2) + 4 * kh;   // local row 0..63
        int cb = (h * 32 + l31) * 2;                             // byte col
        *(__bf16*)(act + rl * 512 + (cb ^ ((rl & 7) << 4))) = (__bf16)acc[reg];
      }
    }
  }
  __syncthreads();

  // ---- phase 2: out = o @ out_w^T + out_b (out stores nt) ----
  const int wc = wid;
  const char* wlane = (const char*)wfin + (size_t)(wc * 2048 + lane) * 16;
  f32x4 acc[4][4];
#pragma unroll
  for (int nr = 0; nr < 4; ++nr)
#pragma unroll
    for (int nc = 0; nc < 4; ++nc)
#pragma unroll
      for (int j = 0; j < 4; ++j) acc[nr][nc][j] = 0.f;

  kloop8(acc, wlane, act, fr, fq);

  float* og = fout + row0 * 256;
#pragma unroll
  for (int nc = 0; nc < 4; ++nc) {
    float4 b4 = *(const float4*)(bias + wc * 64 + nc * 16 + fq * 4);
#pragma unroll
    for (int nr = 0; nr < 4; ++nr) {
      f32x4 st = { acc[nr][nc][0] + b4.x, acc[nr][nc][1] + b4.y,
                   acc[nr][nc][2] + b4.z, acc[nr][nc][3] + b4.w };
      ntstore4(og + (size_t)(nr * 16 + fr) * 256 + wc * 64 + nc * 16 + fq * 4, st);
    }
  }
}

// ---------------- launch ----------------
extern "C" void kernel_launch(void* const* d_in, const int* in_sizes, int n_in,
                              void* d_out, int out_size, void* d_ws, size_t ws_size,
                              hipStream_t stream) {
  const float* x     = (const float*)d_in[0];
  const float* lq    = (const float*)d_in[1];
  const float* kfc1b = (const float*)d_in[3];
  const float* kfcsb = (const float*)d_in[5];
  const float* kfc2b = (const float*)d_in[7];
  const float* vfc1b = (const float*)d_in[9];
  const float* vfcsb = (const float*)d_in[11];
  const float* vfc2b = (const float*)d_in[13];
  const float* mixw  = (const float*)d_in[14];
  const float* outb  = (const float*)d_in[16];

  const int R = in_sizes[0] / 256;          // 131072 rows (B*N)

  char* ws = (char*)d_ws;
  BF16*  wbf   = (BF16*)(ws);                    //  1,179,648 B
  BF16*  wt    = (BF16*)(ws + 1179648);          //    131,072 B
  float* pm    = (float*)(ws + 1310720);         //  2,097,152 B
  float* ps    = (float*)(ws + 3407872);         //  2,097,152 B
  float* Mf    = (float*)(ws + 5505024);         //      4,096 B
  float* Sf    = (float*)(ws + 5509120);         //      4,096 B
  BF16*  zpart = (BF16*)(ws + 5513216);          // 33,554,432 B (2048 x 8192 bf16)
  float* z     = (float*)(ws + 39067648);        //    131,072 B
  float* mixed = (float*)d_out;                  // d_out doubles as mixed (f32)

  // prep
  WPtrs wp = {{(const float*)d_in[2], (const float*)d_in[4], (const float*)d_in[4] + 65536,
               (const float*)d_in[6], (const float*)d_in[8], (const float*)d_in[10],
               (const float*)d_in[10] + 65536, (const float*)d_in[12], (const float*)d_in[15]}};
  cast_w_kernel<<<2304, 256, 0, stream>>>(wp, wbf);
  build_wtilde<<<256, 256, 0, stream>>>(mixw, lq, wt);

  const int G = R / 64;   // 2048

  // k-chain + mixed + stats
  FArgs a1;
  a1.w[0] = wbf + 0;      a1.b[0] = kfc1b;
  a1.w[1] = wbf + 65536;  a1.b[1] = kfcsb;
  a1.w[2] = wbf + 131072; a1.b[2] = kfcsb + 256;
  a1.w[3] = wbf + 196608; a1.b[3] = kfc2b;
  a1.w[4] = wt;           a1.b[4] = nullptr;
  fused_k_mixed<<<G, 256, 0, stream>>>(x, a1, mixed, pm, ps);

  // softmax-over-N merge (Mf/Sf ready before the v-chain)
  softmax_merge<<<4, 256, 0, stream>>>(pm, ps, Mf, Sf);

  // v-chain + z-partials (v never leaves LDS)
  FArgs a2;
  a2.w[0] = wbf + 262144; a2.b[0] = vfc1b;
  a2.w[1] = wbf + 327680; a2.b[1] = vfcsb;
  a2.w[2] = wbf + 393216; a2.b[2] = vfcsb + 256;
  a2.w[3] = wbf + 458752; a2.b[3] = vfc2b;
  a2.w[4] = nullptr;      a2.b[4] = nullptr;
  fused_v_z<<<G, 256, 0, stream>>>(x, a2, mixed, Mf, zpart);

  // z = (sum of partials) * Sf
  z_merge<<<128, 256, 0, stream>>>(zpart, Sf, z);

  // decode + final projection fused (reads mixed, writes d_out in place)
  decode_final<<<G, 256, 0, stream>>>(mixed, z, wbf + 524288, outb, (float*)d_out);
}

// Round 15
// 386.999 us; speedup vs baseline: 1.1193x; 1.1193x over previous
//
#include <hip/hip_runtime.h>
#include <hip/hip_bf16.h>
#include <math.h>

#define BF16 __hip_bfloat16

typedef __bf16 bf16x8 __attribute__((ext_vector_type(8)));
typedef float  f32x4  __attribute__((ext_vector_type(4)));
typedef float  f32x16 __attribute__((ext_vector_type(16)));
typedef int    i32x4  __attribute__((ext_vector_type(4)));

// branch-free erf (Abramowitz-Stegun 7.1.26, |err| < 1.5e-7)
__device__ inline float gelu_erf(float x) {
  float xs = x * 0.70710678118654752f;
  float a = fabsf(xs);
  float t = __builtin_amdgcn_rcpf(1.0f + 0.3275911f * a);
  float p = 1.061405429f;
  p = p * t - 1.453152027f;
  p = p * t + 1.421413741f;
  p = p * t - 0.284496736f;
  p = p * t + 0.254829592f;
  float e = __expf(-a * a);
  float y = 1.0f - p * t * e;
  float s = copysignf(y, xs);
  return 0.5f * x * (1.0f + s);
}

__device__ inline bf16x8 asbf8(i32x4 v) { union { i32x4 i; bf16x8 b; } u; u.i = v; return u.b; }

__device__ inline i32x4 aload16(const char* p) {
  i32x4 d;
  asm volatile("global_load_dwordx4 %0, %1, off" : "=v"(d) : "v"(p));
  return d;
}

template <int N> __device__ inline void vmwait() {
  if constexpr (N == 0)      asm volatile("s_waitcnt vmcnt(0)" ::: "memory");
  else if constexpr (N == 4) asm volatile("s_waitcnt vmcnt(4)" ::: "memory");
  else                       asm volatile("s_waitcnt vmcnt(8)" ::: "memory");
  __builtin_amdgcn_sched_barrier(0);
}

// ---- non-temporal helpers (native ext_vector types) ----
// R14 lesson: nt ONLY on producer-side streams with zero intra-kernel reuse
// (x staging reads, k_mixed's mixed store). Consumer-side nt (mixed reads,
// zpart, out store) regressed ~60us by killing L2 line reuse.
__device__ inline f32x4 ntload4(const float* p) {
  return __builtin_nontemporal_load((const f32x4*)p);
}
__device__ inline void ntstore4(float* p, f32x4 v) {
  __builtin_nontemporal_store(v, (f32x4*)p);
}

struct WPtrs { const float* p[9]; };
struct FArgs { const BF16* w[5]; const float* b[5]; };

// ---------------- small prep kernels ----------------
// Weights in MFMA-fragment order:
//   element = wc*16384 + nc*4096 + kt*512 + (fq*16+fr)*8 + e
//   source  = W[wc*64+nc*16+fr][kt*32+fq*8+e]       (wc: col-group 0..3)
__global__ void cast_w_kernel(WPtrs wp, BF16* __restrict__ out) {
  int i = blockIdx.x * 256 + threadIdx.x;   // < 9*65536
  int seg = i >> 16, d = i & 65535;
  int e = d & 7, lane = (d >> 3) & 63, kt = (d >> 9) & 7;
  int nc = (d >> 12) & 3, wc = (d >> 14) & 3;
  int fr = lane & 15, fq = lane >> 4;
  int row = wc * 64 + nc * 16 + fr, col = kt * 32 + fq * 8 + e;
  out[i] = __float2bfloat16(wp.p[seg][row * 256 + col]);
}

// W~[p, h*32+d] = sum_j mix_w[p, h*32+j] * latent_q[h*32+j, d], fragment-ordered
__global__ void build_wtilde(const float* __restrict__ mixw, const float* __restrict__ lq,
                             BF16* __restrict__ wt) {
  int p = blockIdx.x, c = threadIdx.x;
  int h = c >> 5, d = c & 31;
  float s = 0.f;
#pragma unroll
  for (int j = 0; j < 32; ++j)
    s += mixw[p * 256 + h * 32 + j] * lq[(h * 32 + j) * 32 + d];
  int wc = p >> 6, nc = (p >> 4) & 3, fr = p & 15;
  int kt = c >> 5, fq = (c >> 3) & 3, e = c & 7;
  int dst = ((((wc * 4 + nc) * 8 + kt) * 64) + (fq * 16 + fr)) * 8 + e;
  wt[dst] = __float2bfloat16(s);
}

// ---------------- helpers ----------------
__device__ inline void issue4(i32x4 (&buf)[4], const char* wlane, int kt) {
#pragma unroll
  for (int nc = 0; nc < 4; ++nc)
    buf[nc] = aload16(wlane + (nc * 8 + kt) * 1024);
}

__device__ inline void loada4(bf16x8 (&dst)[4], const char* act, int kt, int fr, int fq) {
#pragma unroll
  for (int nr = 0; nr < 4; ++nr) {
    int r = nr * 16 + fr;
    dst[nr] = *(const bf16x8*)(act + r * 512 + ((kt * 64 + fq * 16) ^ ((r & 7) << 4)));
  }
}

__device__ inline void mfma16w(f32x4 (&acc)[4][4], const i32x4 (&wbuf)[4], const bf16x8 (&af)[4]) {
#pragma unroll
  for (int nr = 0; nr < 4; ++nr)
#pragma unroll
    for (int nc = 0; nc < 4; ++nc)
      acc[nr][nc] = __builtin_amdgcn_mfma_f32_16x16x32_bf16(asbf8(wbuf[nc]), af[nr], acc[nr][nc], 0, 0, 0);
}

// 8-kt pipelined GEMM over the resident act tile (R6-verified structure)
__device__ inline void kloop8(f32x4 (&acc)[4][4], const char* wlane, const char* act,
                              int fr, int fq) {
  i32x4 wb0[4], wb1[4], wb2[4];
  bf16x8 afA[4], afB[4];
  issue4(wb0, wlane, 0);
  issue4(wb1, wlane, 1);
  loada4(afA, act, 0, fr, fq);
  issue4(wb2, wlane, 2); loada4(afB, act, 1, fr, fq);
  vmwait<8>(); mfma16w(acc, wb0, afA);
  issue4(wb0, wlane, 3); loada4(afA, act, 2, fr, fq);
  vmwait<8>(); mfma16w(acc, wb1, afB);
  issue4(wb1, wlane, 4); loada4(afB, act, 3, fr, fq);
  vmwait<8>(); mfma16w(acc, wb2, afA);
  issue4(wb2, wlane, 5); loada4(afA, act, 4, fr, fq);
  vmwait<8>(); mfma16w(acc, wb0, afB);
  issue4(wb0, wlane, 6); loada4(afB, act, 5, fr, fq);
  vmwait<8>(); mfma16w(acc, wb1, afA);
  issue4(wb1, wlane, 7); loada4(afA, act, 6, fr, fq);
  vmwait<8>(); mfma16w(acc, wb2, afB);
  loada4(afB, act, 7, fr, fq);
  vmwait<4>(); mfma16w(acc, wb0, afA);
  vmwait<0>(); mfma16w(acc, wb1, afB);
}

// ---------------- k-chain: 4 MLP layers + mixed + softmax-N stats ----------------
__global__ __launch_bounds__(256, 3) void fused_k_mixed(
    const float* __restrict__ xin, FArgs args,
    float* __restrict__ mixed,
    float* __restrict__ pm, float* __restrict__ ps) {
  __shared__ __align__(16) char act[64 * 512];
  const int tid = threadIdx.x;
  const int blk = blockIdx.x;
  const int wc = tid >> 6, lane = tid & 63;
  const int fr = lane & 15, fq = lane >> 4;
  const size_t row0 = (size_t)blk * 64;

  // ---- stage input tile into swizzled LDS (nt: x is a one-shot stream) ----
  {
    const float* xg = xin + row0 * 256;
#pragma unroll
    for (int rep = 0; rep < 16; ++rep) {
      int i = rep * 256 + tid;               // float4 index in tile (4096 total)
      int r = i >> 6, c4 = (i & 63) << 2;
      f32x4 v = ntload4(xg + r * 256 + c4);
      union { __bf16 h[4]; unsigned long long u; } p;
      p.h[0] = (__bf16)v[0]; p.h[1] = (__bf16)v[1];
      p.h[2] = (__bf16)v[2]; p.h[3] = (__bf16)v[3];
      int byte = r * 512 + ((c4 * 2) ^ ((r & 7) << 4));
      *(unsigned long long*)(act + byte) = p.u;
    }
  }
  __syncthreads();

#pragma unroll 1
  for (int L = 0; L < 5; ++L) {
    const char* wlane = (const char*)args.w[L] + (size_t)(wc * 2048 + lane) * 16;
    f32x4 acc[4][4];
#pragma unroll
    for (int nr = 0; nr < 4; ++nr)
#pragma unroll
      for (int nc = 0; nc < 4; ++nc)
#pragma unroll
        for (int j = 0; j < 4; ++j) acc[nr][nc][j] = 0.f;

    kloop8(acc, wlane, act, fr, fq);
    __syncthreads();   // all act reads done before any epilogue write

    if (L == 4) {
      // mixed epilogue: f32 global (nt producer store) + max/sumexp partials
      float* mg = mixed + row0 * 256;
#pragma unroll
      for (int nc = 0; nc < 4; ++nc) {
#pragma unroll
        for (int nr = 0; nr < 4; ++nr) {
          f32x4 st = { acc[nr][nc][0], acc[nr][nc][1], acc[nr][nc][2], acc[nr][nc][3] };
          ntstore4(mg + (size_t)(nr * 16 + fr) * 256 + wc * 64 + nc * 16 + fq * 4, st);
        }
        float mx[4], sm[4];
#pragma unroll
        for (int jj = 0; jj < 4; ++jj) {
          float m0 = fmaxf(fmaxf(acc[0][nc][jj], acc[1][nc][jj]),
                           fmaxf(acc[2][nc][jj], acc[3][nc][jj]));
#pragma unroll
          for (int d = 1; d < 16; d <<= 1) m0 = fmaxf(m0, __shfl_xor(m0, d));
          float s0 = 0.f;
#pragma unroll
          for (int nr = 0; nr < 4; ++nr) s0 += __expf(acc[nr][nc][jj] - m0);
#pragma unroll
          for (int d = 1; d < 16; d <<= 1) s0 += __shfl_xor(s0, d);
          mx[jj] = m0; sm[jj] = s0;
        }
        if (fr == 0) {
          int col = wc * 64 + nc * 16 + fq * 4;
          *(float4*)(pm + (size_t)blk * 256 + col) = {mx[0], mx[1], mx[2], mx[3]};
          *(float4*)(ps + (size_t)blk * 256 + col) = {sm[0], sm[1], sm[2], sm[3]};
        }
      }
    } else {
      const float* bb = args.b[L];
#pragma unroll
      for (int nc = 0; nc < 4; ++nc) {
        float4 b4 = *(const float4*)(bb + wc * 64 + nc * 16 + fq * 4);
#pragma unroll
        for (int nr = 0; nr < 4; ++nr) {
          int r = nr * 16 + fr;
          int cb2 = wc * 128 + nc * 32 + fq * 8;
          int byte = r * 512 + (cb2 ^ ((r & 7) << 4));
          union { __bf16 h[4]; unsigned long long u; } res, w2;
          res.u = *(unsigned long long*)(act + byte);
          float o0 = acc[nr][nc][0] + b4.x;
          float o1 = acc[nr][nc][1] + b4.y;
          float o2 = acc[nr][nc][2] + b4.z;
          float o3 = acc[nr][nc][3] + b4.w;
          if (L < 3) { o0 = gelu_erf(o0); o1 = gelu_erf(o1);
                       o2 = gelu_erf(o2); o3 = gelu_erf(o3); }
          w2.h[0] = (__bf16)((float)res.h[0] + o0);
          w2.h[1] = (__bf16)((float)res.h[1] + o1);
          w2.h[2] = (__bf16)((float)res.h[2] + o2);
          w2.h[3] = (__bf16)((float)res.h[3] + o3);
          *(unsigned long long*)(act + byte) = w2.u;
        }
      }
      __syncthreads();
    }
  }
}

// ---------------- softmax-over-N merge ----------------
__global__ void softmax_merge(const float* __restrict__ pm, const float* __restrict__ ps,
                              float* __restrict__ Mf, float* __restrict__ Sf) {
  int b = blockIdx.x, t = threadIdx.x;
  const float* pmb = pm + (size_t)b * 512 * 256;
  const float* psb = ps + (size_t)b * 512 * 256;
  float m = -3.0e38f, s = 0.f;
  for (int c = 0; c < 512; ++c) {
    float m2 = pmb[c * 256 + t];
    float s2 = psb[c * 256 + t];
    float mn = fmaxf(m, m2);
    s = s * __expf(m - mn) + s2 * __expf(m2 - mn);
    m = mn;
  }
  Mf[b * 256 + t] = m;
  Sf[b * 256 + t] = 1.f / s;
}

// ---------------- v-chain + fused z-partial ----------------
// v stays in LDS (never hits HBM); z-partials use global Mf; bf16 zpart.
__global__ __launch_bounds__(256, 3) void fused_v_z(
    const float* __restrict__ xin, FArgs args,
    const float* __restrict__ mixed, const float* __restrict__ Mf,
    BF16* __restrict__ zpart) {
  __shared__ __align__(16) char act[64 * 512];
  const int tid = threadIdx.x;
  const int blk = blockIdx.x;
  const int wc = tid >> 6, lane = tid & 63;
  const int fr = lane & 15, fq = lane >> 4;
  const size_t row0 = (size_t)blk * 64;

  // ---- stage input tile into swizzled LDS (nt: one-shot stream) ----
  {
    const float* xg = xin + row0 * 256;
#pragma unroll
    for (int rep = 0; rep < 16; ++rep) {
      int i = rep * 256 + tid;
      int r = i >> 6, c4 = (i & 63) << 2;
      f32x4 v = ntload4(xg + r * 256 + c4);
      union { __bf16 h[4]; unsigned long long u; } p;
      p.h[0] = (__bf16)v[0]; p.h[1] = (__bf16)v[1];
      p.h[2] = (__bf16)v[2]; p.h[3] = (__bf16)v[3];
      int byte = r * 512 + ((c4 * 2) ^ ((r & 7) << 4));
      *(unsigned long long*)(act + byte) = p.u;
    }
  }
  __syncthreads();

  // ---- 4 MLP layers, result stays in act LDS ----
#pragma unroll 1
  for (int L = 0; L < 4; ++L) {
    const char* wlane = (const char*)args.w[L] + (size_t)(wc * 2048 + lane) * 16;
    f32x4 acc[4][4];
#pragma unroll
    for (int nr = 0; nr < 4; ++nr)
#pragma unroll
      for (int nc = 0; nc < 4; ++nc)
#pragma unroll
        for (int j = 0; j < 4; ++j) acc[nr][nc][j] = 0.f;

    kloop8(acc, wlane, act, fr, fq);
    __syncthreads();

    const float* bb = args.b[L];
#pragma unroll
    for (int nc = 0; nc < 4; ++nc) {
      float4 b4 = *(const float4*)(bb + wc * 64 + nc * 16 + fq * 4);
#pragma unroll
      for (int nr = 0; nr < 4; ++nr) {
        int r = nr * 16 + fr;
        int cb2 = wc * 128 + nc * 32 + fq * 8;
        int byte = r * 512 + (cb2 ^ ((r & 7) << 4));
        union { __bf16 h[4]; unsigned long long u; } res, w2;
        res.u = *(unsigned long long*)(act + byte);
        float o0 = acc[nr][nc][0] + b4.x;
        float o1 = acc[nr][nc][1] + b4.y;
        float o2 = acc[nr][nc][2] + b4.z;
        float o3 = acc[nr][nc][3] + b4.w;
        if (L < 3) { o0 = gelu_erf(o0); o1 = gelu_erf(o1);
                     o2 = gelu_erf(o2); o3 = gelu_erf(o3); }
        w2.h[0] = (__bf16)((float)res.h[0] + o0);
        w2.h[1] = (__bf16)((float)res.h[1] + o1);
        w2.h[2] = (__bf16)((float)res.h[2] + o2);
        w2.h[3] = (__bf16)((float)res.h[3] + o3);
        *(unsigned long long*)(act + byte) = w2.u;
      }
    }
    __syncthreads();
  }

  // ---- z-partial phase: v from LDS, enc from exp(mixed - Mf) (regular loads:
  // mixed lines are shared across waves; nt here cost ~60us in R14) ----
  const int l31 = lane & 31, kh = lane >> 5;
  const int b = (int)(row0 >> 15);
  for (int hi = 0; hi < 2; ++hi) {
    int h = wc * 2 + hi;                  // wave wc handles heads 2wc, 2wc+1
    int col = h * 32 + l31;
    float Mp = Mf[b * 256 + col];
    f32x16 zacc;
#pragma unroll
    for (int r = 0; r < 16; ++r) zacc[r] = 0.f;
#pragma unroll
    for (int s = 0; s < 4; ++s) {         // K = 64 rows in 4 steps of 16
      bf16x8 ea, vb;
      int rl0 = s * 16 + kh * 8;
      size_t nbase = row0 + rl0;
#pragma unroll
      for (int j = 0; j < 8; ++j) {
        float xv = __expf(mixed[(nbase + j) * 256 + col] - Mp);
        ea[j] = (__bf16)xv;
        int rl = rl0 + j;
        vb[j] = *(const __bf16*)(act + rl * 512 + ((col * 2) ^ ((rl & 7) << 4)));
      }
      zacc = __builtin_amdgcn_mfma_f32_32x32x16_bf16(ea, vb, zacc, 0, 0, 0);
    }
    BF16* zp = zpart + (size_t)blk * 8192 + h * 1024;
#pragma unroll
    for (int reg = 0; reg < 16; ++reg) {
      int m = (reg & 3) + 8 * (reg >> 2) + 4 * kh;
      zp[m * 32 + l31] = __float2bfloat16(zacc[reg]);
    }
  }
}

__global__ void z_merge(const BF16* __restrict__ zpart, const float* __restrict__ Sf,
                        float* __restrict__ z) {
  int i = blockIdx.x * 256 + threadIdx.x;   // [0, 4*8192)
  int b = i >> 13, j = i & 8191;
  int p = j >> 5;                           // h*32 + m
  float s = 0.f;
  for (int c = 0; c < 512; ++c)
    s += __bfloat162float(zpart[((size_t)(b * 512 + c)) * 8192 + j]);
  z[i] = s * Sf[b * 256 + p];
}

// ---------------- decode + final projection fused ----------------
__global__ __launch_bounds__(256, 3) void decode_final(
    const float* __restrict__ mixed, const float* __restrict__ z,
    const BF16* __restrict__ wfin, const float* __restrict__ bias,
    float* __restrict__ fout) {
  __shared__ __align__(16) char act[64 * 512];
  const int tid = threadIdx.x, blk = blockIdx.x;
  const int wid = tid >> 6, lane = tid & 63;
  const int l31 = lane & 31, kh = lane >> 5;
  const int fr = lane & 15, fq = lane >> 4;
  const size_t row0 = (size_t)blk * 64;
  const int b = (int)(row0 >> 15);

  // ---- phase 1: decode into LDS o-tile (regular mixed reads) ----
  for (int hi = 0; hi < 2; ++hi) {
    int h = (wid << 1) + hi;
    bf16x8 zf[2];
#pragma unroll
    for (int ks = 0; ks < 2; ++ks)
#pragma unroll
      for (int j = 0; j < 8; ++j)
        zf[ks][j] = (__bf16)z[b * 8192 + h * 1024 + (ks * 16 + kh * 8 + j) * 32 + l31];
#pragma unroll 1
    for (int s = 0; s < 2; ++s) {
      size_t n = row0 + s * 32 + l31;
      const float* mrow = mixed + n * 256 + h * 32;
      float xv[16];
#pragma unroll
      for (int ks = 0; ks < 2; ++ks) {
        float4 a  = *(const float4*)(mrow + ks * 16 + kh * 8);
        float4 c4 = *(const float4*)(mrow + ks * 16 + kh * 8 + 4);
        xv[ks * 8 + 0] = a.x;  xv[ks * 8 + 1] = a.y;  xv[ks * 8 + 2] = a.z;  xv[ks * 8 + 3] = a.w;
        xv[ks * 8 + 4] = c4.x; xv[ks * 8 + 5] = c4.y; xv[ks * 8 + 6] = c4.z; xv[ks * 8 + 7] = c4.w;
      }
      float mx = xv[0];
#pragma unroll
      for (int i = 1; i < 16; ++i) mx = fmaxf(mx, xv[i]);
      mx = fmaxf(mx, __shfl_xor(mx, 32));
      float sm = 0.f, ev[16];
#pragma unroll
      for (int i = 0; i < 16; ++i) { ev[i] = __expf(xv[i] - mx); sm += ev[i]; }
      sm += __shfl_xor(sm, 32);
      float inv = 1.f / sm;
      bf16x8 af[2];
#pragma unroll
      for (int ks = 0; ks < 2; ++ks)
#pragma unroll
        for (int j = 0; j < 8; ++j) af[ks][j] = (__bf16)(ev[ks * 8 + j] * inv);
      f32x16 acc;
#pragma unroll
      for (int r = 0; r < 16; ++r) acc[r] = 0.f;
      acc = __builtin_amdgcn_mfma_f32_32x32x16_bf16(af[0], zf[0], acc, 0, 0, 0);
      acc = __builtin_amdgcn_mfma_f32_32x32x16_bf16(af[1], zf[1], acc, 0, 0, 0);
#pragma unroll
      for (int reg = 0; reg < 16; ++reg) {
        int rl = s * 32 + (reg & 3) + 8 * (reg >> 2) + 4 * kh;   // local row 0..63
        int cb = (h * 32 + l31) * 2;                             // byte col
        *(__bf16*)(act + rl * 512 + (cb ^ ((rl & 7) << 4))) = (__bf16)acc[reg];
      }
    }
  }
  __syncthreads();

  // ---- phase 2: out = o @ out_w^T + out_b (regular stores) ----
  const int wc = wid;
  const char* wlane = (const char*)wfin + (size_t)(wc * 2048 + lane) * 16;
  f32x4 acc[4][4];
#pragma unroll
  for (int nr = 0; nr < 4; ++nr)
#pragma unroll
    for (int nc = 0; nc < 4; ++nc)
#pragma unroll
      for (int j = 0; j < 4; ++j) acc[nr][nc][j] = 0.f;

  kloop8(acc, wlane, act, fr, fq);

  float* og = fout + row0 * 256;
#pragma unroll
  for (int nc = 0; nc < 4; ++nc) {
    float4 b4 = *(const float4*)(bias + wc * 64 + nc * 16 + fq * 4);
#pragma unroll
    for (int nr = 0; nr < 4; ++nr) {
      float4 st = { acc[nr][nc][0] + b4.x, acc[nr][nc][1] + b4.y,
                    acc[nr][nc][2] + b4.z, acc[nr][nc][3] + b4.w };
      *(float4*)(og + (size_t)(nr * 16 + fr) * 256 + wc * 64 + nc * 16 + fq * 4) = st;
    }
  }
}

// ---------------- launch ----------------
extern "C" void kernel_launch(void* const* d_in, const int* in_sizes, int n_in,
                              void* d_out, int out_size, void* d_ws, size_t ws_size,
                              hipStream_t stream) {
  const float* x     = (const float*)d_in[0];
  const float* lq    = (const float*)d_in[1];
  const float* kfc1b = (const float*)d_in[3];
  const float* kfcsb = (const float*)d_in[5];
  const float* kfc2b = (const float*)d_in[7];
  const float* vfc1b = (const float*)d_in[9];
  const float* vfcsb = (const float*)d_in[11];
  const float* vfc2b = (const float*)d_in[13];
  const float* mixw  = (const float*)d_in[14];
  const float* outb  = (const float*)d_in[16];

  const int R = in_sizes[0] / 256;          // 131072 rows (B*N)

  char* ws = (char*)d_ws;
  BF16*  wbf   = (BF16*)(ws);                    //  1,179,648 B
  BF16*  wt    = (BF16*)(ws + 1179648);          //    131,072 B
  float* pm    = (float*)(ws + 1310720);         //  2,097,152 B
  float* ps    = (float*)(ws + 3407872);         //  2,097,152 B
  float* Mf    = (float*)(ws + 5505024);         //      4,096 B
  float* Sf    = (float*)(ws + 5509120);         //      4,096 B
  BF16*  zpart = (BF16*)(ws + 5513216);          // 33,554,432 B (2048 x 8192 bf16)
  float* z     = (float*)(ws + 39067648);        //    131,072 B
  float* mixed = (float*)d_out;                  // d_out doubles as mixed (f32)

  // prep
  WPtrs wp = {{(const float*)d_in[2], (const float*)d_in[4], (const float*)d_in[4] + 65536,
               (const float*)d_in[6], (const float*)d_in[8], (const float*)d_in[10],
               (const float*)d_in[10] + 65536, (const float*)d_in[12], (const float*)d_in[15]}};
  cast_w_kernel<<<2304, 256, 0, stream>>>(wp, wbf);
  build_wtilde<<<256, 256, 0, stream>>>(mixw, lq, wt);

  const int G = R / 64;   // 2048

  // k-chain + mixed + stats
  FArgs a1;
  a1.w[0] = wbf + 0;      a1.b[0] = kfc1b;
  a1.w[1] = wbf + 65536;  a1.b[1] = kfcsb;
  a1.w[2] = wbf + 131072; a1.b[2] = kfcsb + 256;
  a1.w[3] = wbf + 196608; a1.b[3] = kfc2b;
  a1.w[4] = wt;           a1.b[4] = nullptr;
  fused_k_mixed<<<G, 256, 0, stream>>>(x, a1, mixed, pm, ps);

  // softmax-over-N merge (Mf/Sf ready before the v-chain)
  softmax_merge<<<4, 256, 0, stream>>>(pm, ps, Mf, Sf);

  // v-chain + z-partials (v never leaves LDS)
  FArgs a2;
  a2.w[0] = wbf + 262144; a2.b[0] = vfc1b;
  a2.w[1] = wbf + 327680; a2.b[1] = vfcsb;
  a2.w[2] = wbf + 393216; a2.b[2] = vfcsb + 256;
  a2.w[3] = wbf + 458752; a2.b[3] = vfc2b;
  a2.w[4] = nullptr;      a2.b[4] = nullptr;
  fused_v_z<<<G, 256, 0, stream>>>(x, a2, mixed, Mf, zpart);

  // z = (sum of partials) * Sf
  z_merge<<<128, 256, 0, stream>>>(zpart, Sf, z);

  // decode + final projection fused (reads mixed, writes d_out in place)
  decode_final<<<G, 256, 0, stream>>>(mixed, z, wbf + 524288, outb, (float*)d_out);
}

// Round 17
// 352.250 us; speedup vs baseline: 1.2298x; 1.0986x over previous
//
#include <hip/hip_runtime.h>
#include <hip/hip_bf16.h>
#include <math.h>

#define BF16 __hip_bfloat16

typedef __bf16 bf16x8 __attribute__((ext_vector_type(8)));
typedef float  f32x4  __attribute__((ext_vector_type(4)));
typedef float  f32x16 __attribute__((ext_vector_type(16)));
typedef int    i32x4  __attribute__((ext_vector_type(4)));

// branch-free erf (Abramowitz-Stegun 7.1.26, |err| < 1.5e-7)
__device__ inline float gelu_erf(float x) {
  float xs = x * 0.70710678118654752f;
  float a = fabsf(xs);
  float t = __builtin_amdgcn_rcpf(1.0f + 0.3275911f * a);
  float p = 1.061405429f;
  p = p * t - 1.453152027f;
  p = p * t + 1.421413741f;
  p = p * t - 0.284496736f;
  p = p * t + 0.254829592f;
  float e = __expf(-a * a);
  float y = 1.0f - p * t * e;
  float s = copysignf(y, xs);
  return 0.5f * x * (1.0f + s);
}

__device__ inline bf16x8 asbf8(i32x4 v) { union { i32x4 i; bf16x8 b; } u; u.i = v; return u.b; }

__device__ inline i32x4 aload16(const char* p) {
  i32x4 d;
  asm volatile("global_load_dwordx4 %0, %1, off" : "=v"(d) : "v"(p));
  return d;
}

template <int N> __device__ inline void vmwait() {
  if constexpr (N == 0)      asm volatile("s_waitcnt vmcnt(0)" ::: "memory");
  else if constexpr (N == 4) asm volatile("s_waitcnt vmcnt(4)" ::: "memory");
  else                       asm volatile("s_waitcnt vmcnt(8)" ::: "memory");
  __builtin_amdgcn_sched_barrier(0);
}

// ---- non-temporal helpers (producer-side streams only; R14/R15 A/B) ----
__device__ inline f32x4 ntload4(const float* p) {
  return __builtin_nontemporal_load((const f32x4*)p);
}
__device__ inline void ntstore4(float* p, f32x4 v) {
  __builtin_nontemporal_store(v, (f32x4*)p);
}

struct WPtrs { const float* p[9]; };
struct FArgs { const BF16* w[5]; const float* b[5]; };

// ---------------- small prep kernels ----------------
// Weights in MFMA-fragment order:
//   element = wc*16384 + nc*4096 + kt*512 + (fq*16+fr)*8 + e
//   source  = W[wc*64+nc*16+fr][kt*32+fq*8+e]       (wc: col-group 0..3)
__global__ void cast_w_kernel(WPtrs wp, BF16* __restrict__ out) {
  int i = blockIdx.x * 256 + threadIdx.x;   // < 9*65536
  int seg = i >> 16, d = i & 65535;
  int e = d & 7, lane = (d >> 3) & 63, kt = (d >> 9) & 7;
  int nc = (d >> 12) & 3, wc = (d >> 14) & 3;
  int fr = lane & 15, fq = lane >> 4;
  int row = wc * 64 + nc * 16 + fr, col = kt * 32 + fq * 8 + e;
  out[i] = __float2bfloat16(wp.p[seg][row * 256 + col]);
}

// W~[p, h*32+d] = sum_j mix_w[p, h*32+j] * latent_q[h*32+j, d], fragment-ordered
__global__ void build_wtilde(const float* __restrict__ mixw, const float* __restrict__ lq,
                             BF16* __restrict__ wt) {
  int p = blockIdx.x, c = threadIdx.x;
  int h = c >> 5, d = c & 31;
  float s = 0.f;
#pragma unroll
  for (int j = 0; j < 32; ++j)
    s += mixw[p * 256 + h * 32 + j] * lq[(h * 32 + j) * 32 + d];
  int wc = p >> 6, nc = (p >> 4) & 3, fr = p & 15;
  int kt = c >> 5, fq = (c >> 3) & 3, e = c & 7;
  int dst = ((((wc * 4 + nc) * 8 + kt) * 64) + (fq * 16 + fr)) * 8 + e;
  wt[dst] = __float2bfloat16(s);
}

// ---------------- helpers ----------------
__device__ inline void issue4(i32x4 (&buf)[4], const char* wlane, int kt) {
#pragma unroll
  for (int nc = 0; nc < 4; ++nc)
    buf[nc] = aload16(wlane + (nc * 8 + kt) * 1024);
}

__device__ inline void loada4(bf16x8 (&dst)[4], const char* act, int kt, int fr, int fq) {
#pragma unroll
  for (int nr = 0; nr < 4; ++nr) {
    int r = nr * 16 + fr;
    dst[nr] = *(const bf16x8*)(act + r * 512 + ((kt * 64 + fq * 16) ^ ((r & 7) << 4)));
  }
}

// 8 act fragments (128 rows) for one kt
__device__ inline void loada8(bf16x8 (&dst)[8], const char* act, int kt, int fr, int fq) {
#pragma unroll
  for (int nr = 0; nr < 8; ++nr) {
    int r = nr * 16 + fr;
    dst[nr] = *(const bf16x8*)(act + r * 512 + ((kt * 64 + fq * 16) ^ ((r & 7) << 4)));
  }
}

__device__ inline void mfma16w(f32x4 (&acc)[4][4], const i32x4 (&wbuf)[4], const bf16x8 (&af)[4]) {
#pragma unroll
  for (int nr = 0; nr < 4; ++nr)
#pragma unroll
    for (int nc = 0; nc < 4; ++nc)
      acc[nr][nc] = __builtin_amdgcn_mfma_f32_16x16x32_bf16(asbf8(wbuf[nc]), af[nr], acc[nr][nc], 0, 0, 0);
}

__device__ inline void mfma32w(f32x4 (&acc)[8][4], const i32x4 (&wbuf)[4], const bf16x8 (&af)[8]) {
#pragma unroll
  for (int nr = 0; nr < 8; ++nr)
#pragma unroll
    for (int nc = 0; nc < 4; ++nc)
      acc[nr][nc] = __builtin_amdgcn_mfma_f32_16x16x32_bf16(asbf8(wbuf[nc]), af[nr], acc[nr][nc], 0, 0, 0);
}

// 8-kt pipelined GEMM, 64-row tile (R6-verified; used by decode_final)
__device__ inline void kloop8(f32x4 (&acc)[4][4], const char* wlane, const char* act,
                              int fr, int fq) {
  i32x4 wb0[4], wb1[4], wb2[4];
  bf16x8 afA[4], afB[4];
  issue4(wb0, wlane, 0);
  issue4(wb1, wlane, 1);
  loada4(afA, act, 0, fr, fq);
  issue4(wb2, wlane, 2); loada4(afB, act, 1, fr, fq);
  vmwait<8>(); mfma16w(acc, wb0, afA);
  issue4(wb0, wlane, 3); loada4(afA, act, 2, fr, fq);
  vmwait<8>(); mfma16w(acc, wb1, afB);
  issue4(wb1, wlane, 4); loada4(afB, act, 3, fr, fq);
  vmwait<8>(); mfma16w(acc, wb2, afA);
  issue4(wb2, wlane, 5); loada4(afA, act, 4, fr, fq);
  vmwait<8>(); mfma16w(acc, wb0, afB);
  issue4(wb0, wlane, 6); loada4(afB, act, 5, fr, fq);
  vmwait<8>(); mfma16w(acc, wb1, afA);
  issue4(wb1, wlane, 7); loada4(afA, act, 6, fr, fq);
  vmwait<8>(); mfma16w(acc, wb2, afB);
  loada4(afB, act, 7, fr, fq);
  vmwait<4>(); mfma16w(acc, wb0, afA);
  vmwait<0>(); mfma16w(acc, wb1, afB);
}

// 8-kt pipelined GEMM, 128-row tile: 3-buffer weight pipeline, weight fragment
// reused across 8 row-fragments -> halves per-row weight L2 traffic.
__device__ inline void kloop8x(f32x4 (&acc)[8][4], const char* wlane, const char* act,
                               int fr, int fq) {
  i32x4 wb0[4], wb1[4], wb2[4];
  bf16x8 af[8];
  issue4(wb0, wlane, 0);
  issue4(wb1, wlane, 1);
  issue4(wb2, wlane, 2); loada8(af, act, 0, fr, fq);
  vmwait<8>(); mfma32w(acc, wb0, af);
  issue4(wb0, wlane, 3); loada8(af, act, 1, fr, fq);
  vmwait<8>(); mfma32w(acc, wb1, af);
  issue4(wb1, wlane, 4); loada8(af, act, 2, fr, fq);
  vmwait<8>(); mfma32w(acc, wb2, af);
  issue4(wb2, wlane, 5); loada8(af, act, 3, fr, fq);
  vmwait<8>(); mfma32w(acc, wb0, af);
  issue4(wb0, wlane, 6); loada8(af, act, 4, fr, fq);
  vmwait<8>(); mfma32w(acc, wb1, af);
  issue4(wb1, wlane, 7); loada8(af, act, 5, fr, fq);
  vmwait<8>(); mfma32w(acc, wb2, af);
  loada8(af, act, 6, fr, fq);
  vmwait<4>(); mfma32w(acc, wb0, af);
  loada8(af, act, 7, fr, fq);
  vmwait<0>(); mfma32w(acc, wb1, af);
}

// ---------------- k-chain: 4 MLP layers + mixed + softmax-N stats ----------------
// 128-row tile, 4 waves x (128 rows x 64 cols), acc[8][4]; launch_bounds(256,2)
// gives VGPR cap 256 so the pipeline registers survive (R8's crush avoided).
__global__ __launch_bounds__(256, 2) void fused_k_mixed(
    const float* __restrict__ xin, FArgs args,
    float* __restrict__ mixed,
    float* __restrict__ pm, float* __restrict__ ps) {
  __shared__ __align__(16) char act[128 * 512];
  const int tid = threadIdx.x;
  const int blk = blockIdx.x;
  const int wc = tid >> 6, lane = tid & 63;
  const int fr = lane & 15, fq = lane >> 4;
  const size_t row0 = (size_t)blk * 128;

  // ---- stage input tile into swizzled LDS (nt producer stream) ----
  {
    const float* xg = xin + row0 * 256;
#pragma unroll
    for (int rep = 0; rep < 32; ++rep) {
      int i = rep * 256 + tid;               // float4 index in tile (8192 total)
      int r = i >> 6, c4 = (i & 63) << 2;
      f32x4 v = ntload4(xg + r * 256 + c4);
      union { __bf16 h[4]; unsigned long long u; } p;
      p.h[0] = (__bf16)v[0]; p.h[1] = (__bf16)v[1];
      p.h[2] = (__bf16)v[2]; p.h[3] = (__bf16)v[3];
      int byte = r * 512 + ((c4 * 2) ^ ((r & 7) << 4));
      *(unsigned long long*)(act + byte) = p.u;
    }
  }
  __syncthreads();

#pragma unroll 1
  for (int L = 0; L < 5; ++L) {
    const char* wlane = (const char*)args.w[L] + (size_t)(wc * 2048 + lane) * 16;
    f32x4 acc[8][4];
#pragma unroll
    for (int nr = 0; nr < 8; ++nr)
#pragma unroll
      for (int nc = 0; nc < 4; ++nc)
#pragma unroll
        for (int j = 0; j < 4; ++j) acc[nr][nc][j] = 0.f;

    kloop8x(acc, wlane, act, fr, fq);
    __syncthreads();   // all act reads done before any epilogue write

    if (L == 4) {
      // mixed epilogue: f32 global (nt producer store) + per-column (128 rows)
      // max/sumexp partials -> one partial row per block
      float* mg = mixed + row0 * 256;
#pragma unroll
      for (int nc = 0; nc < 4; ++nc) {
#pragma unroll
        for (int nr = 0; nr < 8; ++nr) {
          f32x4 st = { acc[nr][nc][0], acc[nr][nc][1], acc[nr][nc][2], acc[nr][nc][3] };
          ntstore4(mg + (size_t)(nr * 16 + fr) * 256 + wc * 64 + nc * 16 + fq * 4, st);
        }
        float mx[4], sm[4];
#pragma unroll
        for (int jj = 0; jj < 4; ++jj) {
          float m0 = acc[0][nc][jj];
#pragma unroll
          for (int nr = 1; nr < 8; ++nr) m0 = fmaxf(m0, acc[nr][nc][jj]);
#pragma unroll
          for (int d = 1; d < 16; d <<= 1) m0 = fmaxf(m0, __shfl_xor(m0, d));
          float s0 = 0.f;
#pragma unroll
          for (int nr = 0; nr < 8; ++nr) s0 += __expf(acc[nr][nc][jj] - m0);
#pragma unroll
          for (int d = 1; d < 16; d <<= 1) s0 += __shfl_xor(s0, d);
          mx[jj] = m0; sm[jj] = s0;
        }
        if (fr == 0) {
          int col = wc * 64 + nc * 16 + fq * 4;
          *(float4*)(pm + (size_t)blk * 256 + col) = {mx[0], mx[1], mx[2], mx[3]};
          *(float4*)(ps + (size_t)blk * 256 + col) = {sm[0], sm[1], sm[2], sm[3]};
        }
      }
    } else {
      const float* bb = args.b[L];
#pragma unroll
      for (int nc = 0; nc < 4; ++nc) {
        float4 b4 = *(const float4*)(bb + wc * 64 + nc * 16 + fq * 4);
#pragma unroll
        for (int nr = 0; nr < 8; ++nr) {
          int r = nr * 16 + fr;
          int cb2 = wc * 128 + nc * 32 + fq * 8;
          int byte = r * 512 + (cb2 ^ ((r & 7) << 4));
          union { __bf16 h[4]; unsigned long long u; } res, w2;
          res.u = *(unsigned long long*)(act + byte);
          float o0 = acc[nr][nc][0] + b4.x;
          float o1 = acc[nr][nc][1] + b4.y;
          float o2 = acc[nr][nc][2] + b4.z;
          float o3 = acc[nr][nc][3] + b4.w;
          if (L < 3) { o0 = gelu_erf(o0); o1 = gelu_erf(o1);
                       o2 = gelu_erf(o2); o3 = gelu_erf(o3); }
          w2.h[0] = (__bf16)((float)res.h[0] + o0);
          w2.h[1] = (__bf16)((float)res.h[1] + o1);
          w2.h[2] = (__bf16)((float)res.h[2] + o2);
          w2.h[3] = (__bf16)((float)res.h[3] + o3);
          *(unsigned long long*)(act + byte) = w2.u;
        }
      }
      __syncthreads();
    }
  }
}

// ---------------- softmax-over-N merge (256 partials per batch) ----------------
__global__ void softmax_merge(const float* __restrict__ pm, const float* __restrict__ ps,
                              float* __restrict__ Mf, float* __restrict__ Sf) {
  int b = blockIdx.x, t = threadIdx.x;
  const float* pmb = pm + (size_t)b * 256 * 256;
  const float* psb = ps + (size_t)b * 256 * 256;
  float m = -3.0e38f, s = 0.f;
  for (int c = 0; c < 256; ++c) {
    float m2 = pmb[c * 256 + t];
    float s2 = psb[c * 256 + t];
    float mn = fmaxf(m, m2);
    s = s * __expf(m - mn) + s2 * __expf(m2 - mn);
    m = mn;
  }
  Mf[b * 256 + t] = m;
  Sf[b * 256 + t] = 1.f / s;
}

// ---------------- v-chain + fused z-partial (128-row tile) ----------------
__global__ __launch_bounds__(256, 2) void fused_v_z(
    const float* __restrict__ xin, FArgs args,
    const float* __restrict__ mixed, const float* __restrict__ Mf,
    BF16* __restrict__ zpart) {
  __shared__ __align__(16) char act[128 * 512];
  const int tid = threadIdx.x;
  const int blk = blockIdx.x;
  const int wc = tid >> 6, lane = tid & 63;
  const int fr = lane & 15, fq = lane >> 4;
  const size_t row0 = (size_t)blk * 128;

  // ---- stage input tile into swizzled LDS (nt producer stream) ----
  {
    const float* xg = xin + row0 * 256;
#pragma unroll
    for (int rep = 0; rep < 32; ++rep) {
      int i = rep * 256 + tid;
      int r = i >> 6, c4 = (i & 63) << 2;
      f32x4 v = ntload4(xg + r * 256 + c4);
      union { __bf16 h[4]; unsigned long long u; } p;
      p.h[0] = (__bf16)v[0]; p.h[1] = (__bf16)v[1];
      p.h[2] = (__bf16)v[2]; p.h[3] = (__bf16)v[3];
      int byte = r * 512 + ((c4 * 2) ^ ((r & 7) << 4));
      *(unsigned long long*)(act + byte) = p.u;
    }
  }
  __syncthreads();

  // ---- 4 MLP layers, result stays in act LDS ----
#pragma unroll 1
  for (int L = 0; L < 4; ++L) {
    const char* wlane = (const char*)args.w[L] + (size_t)(wc * 2048 + lane) * 16;
    f32x4 acc[8][4];
#pragma unroll
    for (int nr = 0; nr < 8; ++nr)
#pragma unroll
      for (int nc = 0; nc < 4; ++nc)
#pragma unroll
        for (int j = 0; j < 4; ++j) acc[nr][nc][j] = 0.f;

    kloop8x(acc, wlane, act, fr, fq);
    __syncthreads();

    const float* bb = args.b[L];
#pragma unroll
    for (int nc = 0; nc < 4; ++nc) {
      float4 b4 = *(const float4*)(bb + wc * 64 + nc * 16 + fq * 4);
#pragma unroll
      for (int nr = 0; nr < 8; ++nr) {
        int r = nr * 16 + fr;
        int cb2 = wc * 128 + nc * 32 + fq * 8;
        int byte = r * 512 + (cb2 ^ ((r & 7) << 4));
        union { __bf16 h[4]; unsigned long long u; } res, w2;
        res.u = *(unsigned long long*)(act + byte);
        float o0 = acc[nr][nc][0] + b4.x;
        float o1 = acc[nr][nc][1] + b4.y;
        float o2 = acc[nr][nc][2] + b4.z;
        float o3 = acc[nr][nc][3] + b4.w;
        if (L < 3) { o0 = gelu_erf(o0); o1 = gelu_erf(o1);
                     o2 = gelu_erf(o2); o3 = gelu_erf(o3); }
        w2.h[0] = (__bf16)((float)res.h[0] + o0);
        w2.h[1] = (__bf16)((float)res.h[1] + o1);
        w2.h[2] = (__bf16)((float)res.h[2] + o2);
        w2.h[3] = (__bf16)((float)res.h[3] + o3);
        *(unsigned long long*)(act + byte) = w2.u;
      }
    }
    __syncthreads();
  }

  // ---- z-partial: v from LDS, enc from exp(mixed - Mf), K=128 rows ----
  const int l31 = lane & 31, kh = lane >> 5;
  const int b = (int)(row0 >> 15);
  for (int hi = 0; hi < 2; ++hi) {
    int h = wc * 2 + hi;                  // wave wc handles heads 2wc, 2wc+1
    int col = h * 32 + l31;
    float Mp = Mf[b * 256 + col];
    f32x16 zacc;
#pragma unroll
    for (int r = 0; r < 16; ++r) zacc[r] = 0.f;
#pragma unroll
    for (int s = 0; s < 8; ++s) {         // K = 128 rows in 8 steps of 16
      bf16x8 ea, vb;
      int rl0 = s * 16 + kh * 8;
      size_t nbase = row0 + rl0;
#pragma unroll
      for (int j = 0; j < 8; ++j) {
        float xv = __expf(mixed[(nbase + j) * 256 + col] - Mp);
        ea[j] = (__bf16)xv;
        int rl = rl0 + j;
        vb[j] = *(const __bf16*)(act + rl * 512 + ((col * 2) ^ ((rl & 7) << 4)));
      }
      zacc = __builtin_amdgcn_mfma_f32_32x32x16_bf16(ea, vb, zacc, 0, 0, 0);
    }
    BF16* zp = zpart + (size_t)blk * 8192 + h * 1024;
#pragma unroll
    for (int reg = 0; reg < 16; ++reg) {
      int m = (reg & 3) + 8 * (reg >> 2) + 4 * kh;
      zp[m * 32 + l31] = __float2bfloat16(zacc[reg]);
    }
  }
}

__global__ void z_merge(const BF16* __restrict__ zpart, const float* __restrict__ Sf,
                        float* __restrict__ z) {
  int i = blockIdx.x * 256 + threadIdx.x;   // [0, 4*8192)
  int b = i >> 13, j = i & 8191;
  int p = j >> 5;                           // h*32 + m
  float s = 0.f;
  for (int c = 0; c < 256; ++c)
    s += __bfloat162float(zpart[((size_t)(b * 256 + c)) * 8192 + j]);
  z[i] = s * Sf[b * 256 + p];
}

// ---------------- decode + final projection fused (64-row blocks) ----------------
__global__ __launch_bounds__(256, 3) void decode_final(
    const float* __restrict__ mixed, const float* __restrict__ z,
    const BF16* __restrict__ wfin, const float* __restrict__ bias,
    float* __restrict__ fout) {
  __shared__ __align__(16) char act[64 * 512];
  const int tid = threadIdx.x, blk = blockIdx.x;
  const int wid = tid >> 6, lane = tid & 63;
  const int l31 = lane & 31, kh = lane >> 5;
  const int fr = lane & 15, fq = lane >> 4;
  const size_t row0 = (size_t)blk * 64;
  const int b = (int)(row0 >> 15);

  // ---- phase 1: decode into LDS o-tile ----
  for (int hi = 0; hi < 2; ++hi) {
    int h = (wid << 1) + hi;
    bf16x8 zf[2];
#pragma unroll
    for (int ks = 0; ks < 2; ++ks)
#pragma unroll
      for (int j = 0; j < 8; ++j)
        zf[ks][j] = (__bf16)z[b * 8192 + h * 1024 + (ks * 16 + kh * 8 + j) * 32 + l31];
#pragma unroll 1
    for (int s = 0; s < 2; ++s) {
      size_t n = row0 + s * 32 + l31;
      const float* mrow = mixed + n * 256 + h * 32;
      float xv[16];
#pragma unroll
      for (int ks = 0; ks < 2; ++ks) {
        float4 a  = *(const float4*)(mrow + ks * 16 + kh * 8);
        float4 c4 = *(const float4*)(mrow + ks * 16 + kh * 8 + 4);
        xv[ks * 8 + 0] = a.x;  xv[ks * 8 + 1] = a.y;  xv[ks * 8 + 2] = a.z;  xv[ks * 8 + 3] = a.w;
        xv[ks * 8 + 4] = c4.x; xv[ks * 8 + 5] = c4.y; xv[ks * 8 + 6] = c4.z; xv[ks * 8 + 7] = c4.w;
      }
      float mx = xv[0];
#pragma unroll
      for (int i = 1; i < 16; ++i) mx = fmaxf(mx, xv[i]);
      mx = fmaxf(mx, __shfl_xor(mx, 32));
      float sm = 0.f, ev[16];
#pragma unroll
      for (int i = 0; i < 16; ++i) { ev[i] = __expf(xv[i] - mx); sm += ev[i]; }
      sm += __shfl_xor(sm, 32);
      float inv = 1.f / sm;
      bf16x8 af[2];
#pragma unroll
      for (int ks = 0; ks < 2; ++ks)
#pragma unroll
        for (int j = 0; j < 8; ++j) af[ks][j] = (__bf16)(ev[ks * 8 + j] * inv);
      f32x16 acc;
#pragma unroll
      for (int r = 0; r < 16; ++r) acc[r] = 0.f;
      acc = __builtin_amdgcn_mfma_f32_32x32x16_bf16(af[0], zf[0], acc, 0, 0, 0);
      acc = __builtin_amdgcn_mfma_f32_32x32x16_bf16(af[1], zf[1], acc, 0, 0, 0);
#pragma unroll
      for (int reg = 0; reg < 16; ++reg) {
        int rl = s * 32 + (reg & 3) + 8 * (reg >> 2) + 4 * kh;   // local row 0..63
        int cb = (h * 32 + l31) * 2;                             // byte col
        *(__bf16*)(act + rl * 512 + (cb ^ ((rl & 7) << 4))) = (__bf16)acc[reg];
      }
    }
  }
  __syncthreads();

  // ---- phase 2: out = o @ out_w^T + out_b ----
  const int wc = wid;
  const char* wlane = (const char*)wfin + (size_t)(wc * 2048 + lane) * 16;
  f32x4 acc[4][4];
#pragma unroll
  for (int nr = 0; nr < 4; ++nr)
#pragma unroll
    for (int nc = 0; nc < 4; ++nc)
#pragma unroll
      for (int j = 0; j < 4; ++j) acc[nr][nc][j] = 0.f;

  kloop8(acc, wlane, act, fr, fq);

  float* og = fout + row0 * 256;
#pragma unroll
  for (int nc = 0; nc < 4; ++nc) {
    float4 b4 = *(const float4*)(bias + wc * 64 + nc * 16 + fq * 4);
#pragma unroll
    for (int nr = 0; nr < 4; ++nr) {
      float4 st = { acc[nr][nc][0] + b4.x, acc[nr][nc][1] + b4.y,
                    acc[nr][nc][2] + b4.z, acc[nr][nc][3] + b4.w };
      *(float4*)(og + (size_t)(nr * 16 + fr) * 256 + wc * 64 + nc * 16 + fq * 4) = st;
    }
  }
}

// ---------------- launch ----------------
extern "C" void kernel_launch(void* const* d_in, const int* in_sizes, int n_in,
                              void* d_out, int out_size, void* d_ws, size_t ws_size,
                              hipStream_t stream) {
  const float* x     = (const float*)d_in[0];
  const float* lq    = (const float*)d_in[1];
  const float* kfc1b = (const float*)d_in[3];
  const float* kfcsb = (const float*)d_in[5];
  const float* kfc2b = (const float*)d_in[7];
  const float* vfc1b = (const float*)d_in[9];
  const float* vfcsb = (const float*)d_in[11];
  const float* vfc2b = (const float*)d_in[13];
  const float* mixw  = (const float*)d_in[14];
  const float* outb  = (const float*)d_in[16];

  const int R = in_sizes[0] / 256;          // 131072 rows (B*N)

  char* ws = (char*)d_ws;
  BF16*  wbf   = (BF16*)(ws);                    //  1,179,648 B
  BF16*  wt    = (BF16*)(ws + 1179648);          //    131,072 B
  float* pm    = (float*)(ws + 1310720);         //  1,048,576 B
  float* ps    = (float*)(ws + 2359296);         //  1,048,576 B
  float* Mf    = (float*)(ws + 3407872);         //      4,096 B
  float* Sf    = (float*)(ws + 3411968);         //      4,096 B
  BF16*  zpart = (BF16*)(ws + 3416064);          // 16,777,216 B (1024 x 8192 bf16)
  float* z     = (float*)(ws + 20193280);        //    131,072 B
  float* mixed = (float*)d_out;                  // d_out doubles as mixed (f32)

  // prep
  WPtrs wp = {{(const float*)d_in[2], (const float*)d_in[4], (const float*)d_in[4] + 65536,
               (const float*)d_in[6], (const float*)d_in[8], (const float*)d_in[10],
               (const float*)d_in[10] + 65536, (const float*)d_in[12], (const float*)d_in[15]}};
  cast_w_kernel<<<2304, 256, 0, stream>>>(wp, wbf);
  build_wtilde<<<256, 256, 0, stream>>>(mixw, lq, wt);

  const int G = R / 128;    // 1024 (MLP kernels, 128-row tiles)
  const int G2 = R / 64;    // 2048 (decode_final, 64-row tiles)

  // k-chain + mixed + stats
  FArgs a1;
  a1.w[0] = wbf + 0;      a1.b[0] = kfc1b;
  a1.w[1] = wbf + 65536;  a1.b[1] = kfcsb;
  a1.w[2] = wbf + 131072; a1.b[2] = kfcsb + 256;
  a1.w[3] = wbf + 196608; a1.b[3] = kfc2b;
  a1.w[4] = wt;           a1.b[4] = nullptr;
  fused_k_mixed<<<G, 256, 0, stream>>>(x, a1, mixed, pm, ps);

  // softmax-over-N merge (Mf/Sf ready before the v-chain)
  softmax_merge<<<4, 256, 0, stream>>>(pm, ps, Mf, Sf);

  // v-chain + z-partials (v never leaves LDS)
  FArgs a2;
  a2.w[0] = wbf + 262144; a2.b[0] = vfc1b;
  a2.w[1] = wbf + 327680; a2.b[1] = vfcsb;
  a2.w[2] = wbf + 393216; a2.b[2] = vfcsb + 256;
  a2.w[3] = wbf + 458752; a2.b[3] = vfc2b;
  a2.w[4] = nullptr;      a2.b[4] = nullptr;
  fused_v_z<<<G, 256, 0, stream>>>(x, a2, mixed, Mf, zpart);

  // z = (sum of partials) * Sf
  z_merge<<<128, 256, 0, stream>>>(zpart, Sf, z);

  // decode + final projection fused (reads mixed, writes d_out in place)
  decode_final<<<G2, 256, 0, stream>>>(mixed, z, wbf + 524288, outb, (float*)d_out);
}